// Round 4
// baseline (409.135 us; speedup 1.0000x reference)
//
#include <hip/hip_runtime.h>

#define HW 256
#define HWMASK 255
#define CH 128
#define BATCH 8
#define NK 4
#define TSX 128
#define TSY 64

// ---------------- Kernel A1: partial sums of guidance ----------------
__global__ __launch_bounds__(256) void mean1_kernel(const float* __restrict__ guid,
                                                    float* __restrict__ partial) {
    int blk = blockIdx.x;
    const float4* p = (const float4*)(guid + (size_t)blk * 16384);
    float s = 0.f;
    for (int i = threadIdx.x; i < 4096; i += 256) {
        float4 v = p[i];
        s += (v.x + v.y) + (v.z + v.w);
    }
    for (int off = 32; off; off >>= 1) s += __shfl_down(s, off, 64);
    __shared__ float red[4];
    if ((threadIdx.x & 63) == 0) red[threadIdx.x >> 6] = s;
    __syncthreads();
    if (threadIdx.x == 0) partial[blk] = (red[0] + red[1]) + (red[2] + red[3]);
}

// ---------------- Kernel B: finalize means + MLP + softmax ----------------
__global__ __launch_bounds__(256) void mlp_kernel(const float* __restrict__ partial,
                                                  const float* __restrict__ w1,
                                                  const float* __restrict__ b1,
                                                  const float* __restrict__ w2,
                                                  const float* __restrict__ b2,
                                                  float* __restrict__ wt) {
    __shared__ float gs[BATCH * CH];
    __shared__ float h1[BATCH * 32];
    __shared__ float lg[BATCH * NK];
    int t = threadIdx.x;
    for (int i = t; i < BATCH * CH; i += 256) {
        float4 v = *(const float4*)(partial + i * 4);
        gs[i] = ((v.x + v.y) + (v.z + v.w)) * (1.0f / 65536.0f);
    }
    __syncthreads();
    {
        int b = t >> 5, j = t & 31;
        float acc = b1[j];
        #pragma unroll 4
        for (int c = 0; c < CH; ++c) acc += gs[b * CH + c] * w1[j * CH + c];
        h1[b * 32 + j] = fmaxf(acc, 0.f);
    }
    __syncthreads();
    if (t < BATCH * NK) {
        int b = t >> 2, k = t & 3;
        float acc = b2[k];
        #pragma unroll
        for (int j = 0; j < 32; ++j) acc += h1[b * 32 + j] * w2[k * 32 + j];
        lg[b * NK + k] = acc;
    }
    __syncthreads();
    if (t < BATCH) {
        int b = t;
        float m = lg[b * 4];
        for (int k = 1; k < 4; ++k) m = fmaxf(m, lg[b * 4 + k]);
        float e[4], s = 0.f;
        for (int k = 0; k < 4; ++k) { e[k] = expf(lg[b * 4 + k] - m); s += e[k]; }
        float inv = 1.0f / s;
        for (int k = 0; k < 4; ++k) wt[b * 4 + k] = e[k] * inv;
    }
}

// ---------------- Kernel C: dyn = blend of basis filters, stored FLIPPED ----------------
__global__ __launch_bounds__(256) void dyn_kernel(const float* __restrict__ wt,
                                                  const float* __restrict__ basis,
                                                  float* __restrict__ dynF) {
    int idx = blockIdx.x * 256 + threadIdx.x;
    if (idx >= BATCH * CH * 49) return;
    int ij = idx % 49;
    int bc = idx / 49;
    int c = bc % CH;
    int b = bc / CH;
    float acc = 0.f;
    #pragma unroll
    for (int k = 0; k < NK; ++k)
        acc += wt[b * NK + k] * basis[(k * CH + c) * 49 + ij];
    dynF[bc * 49 + (48 - ij)] = acc;
}

// ---------------- Kernel D: circular depthwise 7x7 conv, direct-global (no LDS) ----------
__global__ __launch_bounds__(256, 4) void conv_kernel(const float* __restrict__ x,
                                                      const float* __restrict__ dynF,
                                                      float* __restrict__ out) {
    int bc = blockIdx.z;
    const float* xp = x + (size_t)bc * (HW * HW);

    // filter taps: block-uniform address -> scalar loads into SGPRs
    const float* df = dynF + bc * 49;
    float d[49];
    #pragma unroll
    for (int i = 0; i < 49; ++i) d[i] = df[i];

    int tid = threadIdx.x;
    int tx = tid & 15, ty = tid >> 4;        // 16 x 16 threads
    int xb = blockIdx.x * TSX + 8 * tx;      // 8-wide strip
    int yb = blockIdx.y * TSY + 4 * ty;      // 4 rows

    // wrapped column offsets for the 4 quads (cols xb-4 .. xb+11)
    int gx0 = (xb - 4) & HWMASK;
    int gx1 = (xb    ) & HWMASK;
    int gx2 = (xb + 4) & HWMASK;
    int gx3 = (xb + 8) & HWMASK;

    float acc[4][8] = {};
    #pragma unroll
    for (int rr = 0; rr < 10; ++rr) {
        int gy = (yb + rr - 3) & HWMASK;
        const float* rp = xp + gy * HW;
        float4 A = *(const float4*)(rp + gx0);
        float4 B = *(const float4*)(rp + gx1);
        float4 C = *(const float4*)(rp + gx2);
        float4 D = *(const float4*)(rp + gx3);
        float v[16] = {A.x, A.y, A.z, A.w, B.x, B.y, B.z, B.w,
                       C.x, C.y, C.z, C.w, D.x, D.y, D.z, D.w};
        #pragma unroll
        for (int rq = 0; rq < 4; ++rq) {
            int ii = rr - rq;
            if (ii >= 0 && ii <= 6) {
                #pragma unroll
                for (int q = 0; q < 8; ++q) {
                    #pragma unroll
                    for (int jj = 0; jj < 7; ++jj)
                        acc[rq][q] += d[ii * 7 + jj] * v[q + jj + 1];
                }
            }
        }
    }
    float* op = out + (size_t)bc * (HW * HW) + xb;
    #pragma unroll
    for (int rq = 0; rq < 4; ++rq) {
        float4 o0 = {acc[rq][0], acc[rq][1], acc[rq][2], acc[rq][3]};
        float4 o1 = {acc[rq][4], acc[rq][5], acc[rq][6], acc[rq][7]};
        float* row = op + (yb + rq) * HW;
        *(float4*)(row)     = o0;
        *(float4*)(row + 4) = o1;
    }
}

extern "C" void kernel_launch(void* const* d_in, const int* in_sizes, int n_in,
                              void* d_out, int out_size, void* d_ws, size_t ws_size,
                              hipStream_t stream) {
    const float* x        = (const float*)d_in[0];
    const float* guidance = (const float*)d_in[1];
    const float* basis    = (const float*)d_in[2];
    const float* w1       = (const float*)d_in[3];
    const float* b1       = (const float*)d_in[4];
    const float* w2       = (const float*)d_in[5];
    const float* b2       = (const float*)d_in[6];
    float* out = (float*)d_out;
    float* ws  = (float*)d_ws;

    float* partial = ws;                  // 4096
    float* wt      = ws + 4096;           // 32
    float* dynF    = ws + 4096 + 32;      // 50176

    mean1_kernel<<<4096, 256, 0, stream>>>(guidance, partial);
    mlp_kernel<<<1, 256, 0, stream>>>(partial, w1, b1, w2, b2, wt);
    dyn_kernel<<<(BATCH * CH * 49 + 255) / 256, 256, 0, stream>>>(wt, basis, dynF);
    conv_kernel<<<dim3(HW / TSX, HW / TSY, BATCH * CH), 256, 0, stream>>>(x, dynF, out);
}

// Round 5
// 209.800 us; speedup vs baseline: 1.9501x; 1.9501x over previous
//
#include <hip/hip_runtime.h>

#define HW 256
#define HWMASK 255
#define CH 128
#define BATCH 8
#define NK 4
#define TSY 16
#define NQROW 66          // quads per LDS row: cols -4..259 (wrapped), 264 floats
#define NROWS 22          // 16 + 3 halo each side
#define NSTAGE (NROWS * NQROW)   // 1452 quads

// ---------------- Kernel A1: partial sums of guidance ----------------
__global__ __launch_bounds__(256) void mean1_kernel(const float* __restrict__ guid,
                                                    float* __restrict__ partial) {
    int blk = blockIdx.x;
    const float4* p = (const float4*)(guid + (size_t)blk * 16384);
    float s = 0.f;
    for (int i = threadIdx.x; i < 4096; i += 256) {
        float4 v = p[i];
        s += (v.x + v.y) + (v.z + v.w);
    }
    for (int off = 32; off; off >>= 1) s += __shfl_down(s, off, 64);
    __shared__ float red[4];
    if ((threadIdx.x & 63) == 0) red[threadIdx.x >> 6] = s;
    __syncthreads();
    if (threadIdx.x == 0) partial[blk] = (red[0] + red[1]) + (red[2] + red[3]);
}

// ---------------- Kernel B: finalize means + MLP + softmax ----------------
__global__ __launch_bounds__(256) void mlp_kernel(const float* __restrict__ partial,
                                                  const float* __restrict__ w1,
                                                  const float* __restrict__ b1,
                                                  const float* __restrict__ w2,
                                                  const float* __restrict__ b2,
                                                  float* __restrict__ wt) {
    __shared__ float gs[BATCH * CH];
    __shared__ float h1[BATCH * 32];
    __shared__ float lg[BATCH * NK];
    int t = threadIdx.x;
    for (int i = t; i < BATCH * CH; i += 256) {
        float4 v = *(const float4*)(partial + i * 4);
        gs[i] = ((v.x + v.y) + (v.z + v.w)) * (1.0f / 65536.0f);
    }
    __syncthreads();
    {
        int b = t >> 5, j = t & 31;
        float acc = b1[j];
        #pragma unroll 4
        for (int c = 0; c < CH; ++c) acc += gs[b * CH + c] * w1[j * CH + c];
        h1[b * 32 + j] = fmaxf(acc, 0.f);
    }
    __syncthreads();
    if (t < BATCH * NK) {
        int b = t >> 2, k = t & 3;
        float acc = b2[k];
        #pragma unroll
        for (int j = 0; j < 32; ++j) acc += h1[b * 32 + j] * w2[k * 32 + j];
        lg[b * NK + k] = acc;
    }
    __syncthreads();
    if (t < BATCH) {
        int b = t;
        float m = lg[b * 4];
        for (int k = 1; k < 4; ++k) m = fmaxf(m, lg[b * 4 + k]);
        float e[4], s = 0.f;
        for (int k = 0; k < 4; ++k) { e[k] = expf(lg[b * 4 + k] - m); s += e[k]; }
        float inv = 1.0f / s;
        for (int k = 0; k < 4; ++k) wt[b * 4 + k] = e[k] * inv;
    }
}

// ---------------- Kernel C: dyn = blend of basis filters, stored FLIPPED ----------------
__global__ __launch_bounds__(256) void dyn_kernel(const float* __restrict__ wt,
                                                  const float* __restrict__ basis,
                                                  float* __restrict__ dynF) {
    int idx = blockIdx.x * 256 + threadIdx.x;
    if (idx >= BATCH * CH * 49) return;
    int ij = idx % 49;
    int bc = idx / 49;
    int c = bc % CH;
    int b = bc / CH;
    float acc = 0.f;
    #pragma unroll
    for (int k = 0; k < NK; ++k)
        acc += wt[b * NK + k] * basis[(k * CH + c) * 49 + ij];
    dynF[bc * 49 + (48 - ij)] = acc;
}

// ---------------- Kernel D: circular depthwise 7x7 conv, 256x16 row-tile ----------------
// All memory patterns linear: 1KB-contiguous global row reads, linear LDS (no pad,
// no swizzle -> conflict-free for this thread mapping), 1KB-contiguous stores/instr.
__global__ __launch_bounds__(256) void conv_kernel(const float* __restrict__ x,
                                                   const float* __restrict__ dynF,
                                                   float* __restrict__ out) {
    int bc = blockIdx.y;
    int y0 = blockIdx.x * TSY;
    __shared__ float4 lds4[NSTAGE];
    const float* xp = x + (size_t)bc * (HW * HW);

    // filter taps: block-uniform address -> scalar loads into SGPRs
    const float* df = dynF + bc * 49;
    float d[49];
    #pragma unroll
    for (int i = 0; i < 49; ++i) d[i] = df[i];

    // stage 22 rows x 66 quads; LDS float col L = global col L-4 (wrapped)
    int tid = threadIdx.x;
    #pragma unroll
    for (int it = 0; it < 6; ++it) {
        int e = it * 256 + tid;
        if (e < NSTAGE) {
            int r = e / NQROW, c = e - r * NQROW;
            int gy = (y0 + r - 3) & HWMASK;
            int gx = (4 * c - 4) & HWMASK;
            lds4[e] = *(const float4*)(xp + gy * HW + gx);
        }
    }
    __syncthreads();

    int tx = tid & 63, ty = tid >> 6;   // wave = 64 lanes along x; ty = wave id (0..3)
    int ly0 = 4 * ty;                   // output rows within tile
    float acc[4][4] = {};
    #pragma unroll
    for (int rr = 0; rr < 10; ++rr) {
        const float4* rp = &lds4[(ly0 + rr) * NQROW + tx];
        float4 A = rp[0], B = rp[1], C = rp[2];
        float v[12] = {A.x, A.y, A.z, A.w, B.x, B.y, B.z, B.w, C.x, C.y, C.z, C.w};
        #pragma unroll
        for (int rq = 0; rq < 4; ++rq) {
            int ii = rr - rq;
            if (ii >= 0 && ii <= 6) {
                #pragma unroll
                for (int q = 0; q < 4; ++q) {
                    #pragma unroll
                    for (int jj = 0; jj < 7; ++jj)
                        acc[rq][q] += d[ii * 7 + jj] * v[q + jj + 1];
                }
            }
        }
    }
    float* op = out + (size_t)bc * (HW * HW) + 4 * tx;
    #pragma unroll
    for (int rq = 0; rq < 4; ++rq) {
        float4 o = {acc[rq][0], acc[rq][1], acc[rq][2], acc[rq][3]};
        *(float4*)(op + (y0 + ly0 + rq) * HW) = o;
    }
}

extern "C" void kernel_launch(void* const* d_in, const int* in_sizes, int n_in,
                              void* d_out, int out_size, void* d_ws, size_t ws_size,
                              hipStream_t stream) {
    const float* x        = (const float*)d_in[0];
    const float* guidance = (const float*)d_in[1];
    const float* basis    = (const float*)d_in[2];
    const float* w1       = (const float*)d_in[3];
    const float* b1       = (const float*)d_in[4];
    const float* w2       = (const float*)d_in[5];
    const float* b2       = (const float*)d_in[6];
    float* out = (float*)d_out;
    float* ws  = (float*)d_ws;

    float* partial = ws;                  // 4096
    float* wt      = ws + 4096;           // 32
    float* dynF    = ws + 4096 + 32;      // 50176

    mean1_kernel<<<4096, 256, 0, stream>>>(guidance, partial);
    mlp_kernel<<<1, 256, 0, stream>>>(partial, w1, b1, w2, b2, wt);
    dyn_kernel<<<(BATCH * CH * 49 + 255) / 256, 256, 0, stream>>>(wt, basis, dynF);
    conv_kernel<<<dim3(HW / TSY, BATCH * CH), 256, 0, stream>>>(x, dynF, out);
}

// Round 7
// 192.357 us; speedup vs baseline: 2.1270x; 1.0907x over previous
//
#include <hip/hip_runtime.h>

#define HW 256
#define HWMASK 255
#define CH 128
#define BATCH 8
#define NK 4
#define TSY 16
#define NQROW 66                 // quads per LDS row: cols -4..259 wrapped
#define NROWS 22                 // 16 + 3 halo each side
#define NSTAGE (NROWS * NQROW)   // 1452 quads = 23232 B per buffer
#define NT 8                     // tiles per block (128 rows)

typedef float f32x4 __attribute__((ext_vector_type(4)));

__device__ __forceinline__ void load_lds16(const void* g, void* l) {
    __builtin_amdgcn_global_load_lds((const __attribute__((address_space(1))) void*)g,
                                     (__attribute__((address_space(3))) void*)l, 16, 0, 0);
}

// ---------------- Kernel A1: partial sums of guidance ----------------
__global__ __launch_bounds__(256) void mean1_kernel(const float* __restrict__ guid,
                                                    float* __restrict__ partial) {
    int blk = blockIdx.x;
    const float4* p = (const float4*)(guid + (size_t)blk * 16384);
    float s = 0.f;
    for (int i = threadIdx.x; i < 4096; i += 256) {
        float4 v = p[i];
        s += (v.x + v.y) + (v.z + v.w);
    }
    for (int off = 32; off; off >>= 1) s += __shfl_down(s, off, 64);
    __shared__ float red[4];
    if ((threadIdx.x & 63) == 0) red[threadIdx.x >> 6] = s;
    __syncthreads();
    if (threadIdx.x == 0) partial[blk] = (red[0] + red[1]) + (red[2] + red[3]);
}

// ---------------- Kernel B: finalize means + MLP + softmax ----------------
__global__ __launch_bounds__(256) void mlp_kernel(const float* __restrict__ partial,
                                                  const float* __restrict__ w1,
                                                  const float* __restrict__ b1,
                                                  const float* __restrict__ w2,
                                                  const float* __restrict__ b2,
                                                  float* __restrict__ wt) {
    __shared__ float gs[BATCH * CH];
    __shared__ float h1[BATCH * 32];
    __shared__ float lg[BATCH * NK];
    int t = threadIdx.x;
    for (int i = t; i < BATCH * CH; i += 256) {
        float4 v = *(const float4*)(partial + i * 4);
        gs[i] = ((v.x + v.y) + (v.z + v.w)) * (1.0f / 65536.0f);
    }
    __syncthreads();
    {
        int b = t >> 5, j = t & 31;
        float acc = b1[j];
        #pragma unroll 4
        for (int c = 0; c < CH; ++c) acc += gs[b * CH + c] * w1[j * CH + c];
        h1[b * 32 + j] = fmaxf(acc, 0.f);
    }
    __syncthreads();
    if (t < BATCH * NK) {
        int b = t >> 2, k = t & 3;
        float acc = b2[k];
        #pragma unroll
        for (int j = 0; j < 32; ++j) acc += h1[b * 32 + j] * w2[k * 32 + j];
        lg[b * NK + k] = acc;
    }
    __syncthreads();
    if (t < BATCH) {
        int b = t;
        float m = lg[b * 4];
        for (int k = 1; k < 4; ++k) m = fmaxf(m, lg[b * 4 + k]);
        float e[4], s = 0.f;
        for (int k = 0; k < 4; ++k) { e[k] = expf(lg[b * 4 + k] - m); s += e[k]; }
        float inv = 1.0f / s;
        for (int k = 0; k < 4; ++k) wt[b * 4 + k] = e[k] * inv;
    }
}

// ---------------- Kernel C: dyn = blend of basis filters, stored FLIPPED ----------------
__global__ __launch_bounds__(256) void dyn_kernel(const float* __restrict__ wt,
                                                  const float* __restrict__ basis,
                                                  float* __restrict__ dynF) {
    int idx = blockIdx.x * 256 + threadIdx.x;
    if (idx >= BATCH * CH * 49) return;
    int ij = idx % 49;
    int bc = idx / 49;
    int c = bc % CH;
    int b = bc / CH;
    float acc = 0.f;
    #pragma unroll
    for (int k = 0; k < NK; ++k)
        acc += wt[b * NK + k] * basis[(k * CH + c) * 49 + ij];
    dynF[bc * 49 + (48 - ij)] = acc;
}

// ---------------- Kernel D: circular depthwise 7x7 conv ----------------
// Persistent over NT y-tiles, double-buffered LDS, global_load_lds prefetch of
// tile t+1 overlapped with compute of tile t; counted vmcnt (never drains stores).
__global__ __launch_bounds__(256) void conv_kernel(const float* __restrict__ x,
                                                   const float* __restrict__ dynF,
                                                   float* __restrict__ out) {
    int bc = blockIdx.x;                  // 0..1023
    int ybase = blockIdx.y * (NT * TSY);  // 0 or 128
    __shared__ float4 lds4[2][NSTAGE];
    const float* xp = x + (size_t)bc * (HW * HW);
    float* op = out + (size_t)bc * (HW * HW);
    int tid = threadIdx.x;

    // filter taps: block-uniform address -> scalar loads into SGPRs
    const float* df = dynF + bc * 49;
    float d[49];
    #pragma unroll
    for (int i = 0; i < 49; ++i) d[i] = df[i];

    // prologue: stage tile 0 into buf 0
    {
        #pragma unroll
        for (int it = 0; it < 6; ++it) {
            int e = (it < 5) ? it * 256 + tid : (NSTAGE - 256) + tid;
            int r = e / NQROW, c = e - r * NQROW;
            int gy = (ybase + r - 3) & HWMASK;
            int gx = (4 * c - 4) & HWMASK;
            load_lds16(xp + gy * HW + gx, &lds4[0][e]);
        }
    }
    asm volatile("s_waitcnt vmcnt(0)" ::: "memory");
    __builtin_amdgcn_s_barrier();

    int tx = tid & 63, ty = tid >> 6;
    int ly0 = 4 * ty;

    #pragma unroll 1
    for (int t = 0; t < NT; ++t) {
        // issue prefetch of next tile into the other buffer
        if (t + 1 < NT) {
            int y1 = ybase + (t + 1) * TSY;
            float4* nb = lds4[(t + 1) & 1];
            #pragma unroll
            for (int it = 0; it < 6; ++it) {
                int e = (it < 5) ? it * 256 + tid : (NSTAGE - 256) + tid;
                int r = e / NQROW, c = e - r * NQROW;
                int gy = (y1 + r - 3) & HWMASK;
                int gx = (4 * c - 4) & HWMASK;
                load_lds16(xp + gy * HW + gx, &nb[e]);
            }
        }
        // compute current tile
        int y0 = ybase + t * TSY;
        const float4* LB = lds4[t & 1];
        float acc[4][4] = {};
        #pragma unroll
        for (int rr = 0; rr < 10; ++rr) {
            const float4* rp = &LB[(ly0 + rr) * NQROW + tx];
            float4 A = rp[0], B = rp[1], C = rp[2];
            float v[12] = {A.x, A.y, A.z, A.w, B.x, B.y, B.z, B.w, C.x, C.y, C.z, C.w};
            #pragma unroll
            for (int rq = 0; rq < 4; ++rq) {
                int ii = rr - rq;
                if (ii >= 0 && ii <= 6) {
                    #pragma unroll
                    for (int q = 0; q < 4; ++q) {
                        #pragma unroll
                        for (int jj = 0; jj < 7; ++jj)
                            acc[rq][q] += d[ii * 7 + jj] * v[q + jj + 1];
                    }
                }
            }
        }
        #pragma unroll
        for (int rq = 0; rq < 4; ++rq) {
            f32x4 o = {acc[rq][0], acc[rq][1], acc[rq][2], acc[rq][3]};
            __builtin_nontemporal_store(o, (f32x4*)(op + (y0 + ly0 + rq) * HW + 4 * tx));
        }
        // drain prefetch loads (in-order vmcnt: 4 newest = our stores may remain)
        asm volatile("s_waitcnt vmcnt(4)" ::: "memory");
        __builtin_amdgcn_s_barrier();
    }
}

extern "C" void kernel_launch(void* const* d_in, const int* in_sizes, int n_in,
                              void* d_out, int out_size, void* d_ws, size_t ws_size,
                              hipStream_t stream) {
    const float* x        = (const float*)d_in[0];
    const float* guidance = (const float*)d_in[1];
    const float* basis    = (const float*)d_in[2];
    const float* w1       = (const float*)d_in[3];
    const float* b1       = (const float*)d_in[4];
    const float* w2       = (const float*)d_in[5];
    const float* b2       = (const float*)d_in[6];
    float* out = (float*)d_out;
    float* ws  = (float*)d_ws;

    float* partial = ws;                  // 4096
    float* wt      = ws + 4096;           // 32
    float* dynF    = ws + 4096 + 32;      // 50176

    mean1_kernel<<<4096, 256, 0, stream>>>(guidance, partial);
    mlp_kernel<<<1, 256, 0, stream>>>(partial, w1, b1, w2, b2, wt);
    dyn_kernel<<<(BATCH * CH * 49 + 255) / 256, 256, 0, stream>>>(wt, basis, dynF);
    conv_kernel<<<dim3(BATCH * CH, HW / (NT * TSY)), 256, 0, stream>>>(x, dynF, out);
}